// Round 14
// baseline (82.685 us; speedup 1.0000x reference)
//
#include <hip/hip_runtime.h>
#include <float.h>

#define BB 16
#define CC 64
#define NN 2048
#define KNN 3
#define COUT 64
#define SPL 4      // candidate splits; 512 cands/split -> 9-bit local idx
#define TILES 16   // 32-cand tiles per split

typedef _Float16 half8 __attribute__((ext_vector_type(8)));
typedef float f32x16 __attribute__((ext_vector_type(16)));
typedef unsigned long long u64;

union u4h8 { uint4 v; half8 h; };

// async global->LDS, 16B per lane, wave-uniform LDS base (HW adds lane*16)
__device__ __forceinline__ void gl_lds16(const void* g, void* l) {
    __builtin_amdgcn_global_load_lds(
        (const __attribute__((address_space(1))) unsigned*)g,
        (__attribute__((address_space(3))) unsigned*)l, 16, 0, 0);
}

// order-preserving float->unsigned: monotone increasing
__device__ __forceinline__ unsigned ordf(float f) {
    unsigned b = __float_as_uint(f);
    return b ^ (unsigned)(((int)b >> 31) | 0x80000000);
}

// ---------------------------------------------------------------------------
// K1: from x[b][c][n] produce:
//   xe[b][ct][kblk][lane] (16B fp16x8 MFMA fragments of ext=[hi|lo], K=128)
//   anc[b][ct][l<32] (packed fp16 pair (-nc/2 hi, -nc/2 lo))
// Fragment convention: row m = lane&31, k = kblk*16 + 8*(lane>>5) + j.
// kblk 0..3 = hi(x[c]) (c = k), kblk 4..7 = lo residual (c = k-64).
// ---------------------------------------------------------------------------
__global__ __launch_bounds__(256) void k_prep(const float* __restrict__ x,
                                              uint4* __restrict__ xe,
                                              unsigned* __restrict__ anc) {
    __shared__ float t[64][65];
    __shared__ float nsh[64];
    const int b = blockIdx.x;
    const int n0 = blockIdx.y * 64;
    const int tid = threadIdx.x;
    const int ln = tid & 63, g = tid >> 6;
#pragma unroll
    for (int i = 0; i < 16; ++i) {
        const int c = g + 4 * i;
        t[c][ln] = x[((size_t)b * CC + c) * NN + n0 + ln];
    }
    __syncthreads();
    if (tid < 64) {
        float s = 0.f;
#pragma unroll
        for (int c = 0; c < 64; ++c) s = fmaf(t[c][tid], t[c][tid], s);
        nsh[tid] = s;
    }
#pragma unroll
    for (int i = 0; i < 4; ++i) {
        const int cid = tid + 256 * i;
        const int lane = cid & 63;
        const int kblk = (cid >> 6) & 7;
        const int ctl = cid >> 9;               // 0..1
        const int m = ctl * 32 + (lane & 31);   // local point
        const int khalf = (lane >> 5) * 8;
        union { uint4 v; _Float16 h[8]; } pk;
#pragma unroll
        for (int j = 0; j < 8; ++j) {
            const int kg = kblk * 16 + khalf + j;
            const int ch = kg & 63;
            const float f = t[ch][m];
            const _Float16 hi = (_Float16)f;
            pk.h[j] = (kg < 64) ? hi : (_Float16)(f - (float)hi);
        }
        const int ct = (n0 >> 5) + ctl;
        xe[((size_t)(b * 64 + ct) * 8 + kblk) * 64 + lane] = pk.v;
    }
    __syncthreads();
    if (tid < 64) {
        const int ctl = tid >> 5, l = tid & 31;
        const int ct = (n0 >> 5) + ctl;
        const float h = -0.5f * nsh[ctl * 32 + l];
        const _Float16 a0 = (_Float16)h;
        const _Float16 a1 = (_Float16)(h - (float)a0);
        union { unsigned u; _Float16 hh[2]; } cu;
        cu.hh[0] = a0; cu.hh[1] = a1;
        anc[(size_t)(b * 64 + ct) * 32 + l] = cu.u;
    }
}

// ---------------------------------------------------------------------------
// K1b: pack W into fp16 B-fragments. Wf[((kk*2+ct2)*4+kb)*64 + lane]:
// co = ct2*32 + (lane&31), c = kb*16 + 8*(lane>>5) + j, value = fp16(W[co][c][kk])
// ---------------------------------------------------------------------------
__global__ __launch_bounds__(256) void k_wprep(const float* __restrict__ W,
                                               uint4* __restrict__ Wf) {
    const int tid = threadIdx.x;
#pragma unroll
    for (int i = 0; i < 6; ++i) {
        const int id = tid + 256 * i;
        const int l = id & 63;
        const int kb = (id >> 6) & 3;
        const int ct2 = (id >> 8) & 1;
        const int kk = id >> 9;
        const int co = ct2 * 32 + (l & 31);
        union { uint4 v; _Float16 h[8]; } pk;
#pragma unroll
        for (int j = 0; j < 8; ++j) {
            const int c = kb * 16 + 8 * (l >> 5) + j;
            pk.h[j] = (_Float16)W[(co * CC + c) * KNN + kk];
        }
        Wf[id] = pk.v;
    }
}

// ---------------------------------------------------------------------------
// K2: MFMA top-3 with branchless 64-BIT packed-key scan.
// u = (ordf(exact fp32 key) << 32) | (511 - local_idx): descending key with
// ascending-idx tie-break == u64 max. FULL key precision (r12/r13 bug: 9-bit
// truncation's 3e-3 granularity flipped real ranks; rank flips cost O(1)).
// Semantics identical to the passing r11 kernel. Top-3 update = 5-op network.
// Block = 8 waves, QG=1/wave, depth-1 LDS dbuf of candidate tiles.
// 13 MFMA/tile (hihi/hilo/lohi + norm; lolo < 1e-6, dropped).
// bid = qb*64 + (b*4+s): blocks sharing candidate range (b,s) share XCD.
// ---------------------------------------------------------------------------
__global__ __launch_bounds__(512, 4) void k_top3(const uint4* __restrict__ xe,
                                                 const unsigned* __restrict__ anc,
                                                 u64* __restrict__ pk) {
    __shared__ uint4 buf[2][8][64];  // 2 x 8KB candidate tiles
    const int bid = blockIdx.x;      // 512 blocks
    const int qb = bid >> 6;         // query block 0..7
    const int rem = bid & 63;
    const int b = rem >> 2;
    const int s = rem & 3;

    const int tid = threadIdx.x;
    const int lane = tid & 63;
    const int w = tid >> 6;          // wave 0..7
    const int qg = qb * 8 + w;       // this wave's query group (32 queries)

    const uint4* xb = xe + (size_t)(b * 64) * 512;  // tile stride 8*64 uint4
    const int ct0 = s * TILES;

    // prologue: stage tile 0 (1 KB chunk per wave)
    gl_lds16(xb + ((size_t)ct0 * 8 + w) * 64 + lane, &buf[0][w][0]);

    half8 bq[8];
#pragma unroll
    for (int kb = 0; kb < 8; ++kb) {
        u4h8 tq;
        tq.v = xe[((size_t)(b * 64 + qg) * 8 + kb) * 64 + lane];
        bq[kb] = tq.h;
    }
    unsigned av_u[TILES];
#pragma unroll
    for (int t = 0; t < TILES; ++t)
        av_u[t] = anc[(size_t)(b * 64 + ct0 + t) * 32 + (lane & 31)];

    half8 bnc = {};
    if (lane < 32) { bnc[0] = (_Float16)1.0f; bnc[1] = (_Float16)1.0f; }

    u64 k0 = 0ull, k1 = 0ull, k2 = 0ull;  // packed, descending
    const int hi4 = (lane >> 5) * 4;

    __syncthreads();

#pragma unroll
    for (int t = 0; t < TILES; ++t) {
        const int bi = t & 1;
        if (t + 1 < TILES)  // stage next tile into the buffer freed at t-1
            gl_lds16(xb + ((size_t)(ct0 + t + 1) * 8 + w) * 64 + lane,
                     &buf[bi ^ 1][w][0]);

        f32x16 acc = {};
        {
            u4h8 ah[4];
#pragma unroll
            for (int kb = 0; kb < 4; ++kb) ah[kb].v = buf[bi][kb][lane];
#pragma unroll
            for (int kb = 0; kb < 4; ++kb)  // hihi
                acc = __builtin_amdgcn_mfma_f32_32x32x16_f16(ah[kb].h, bq[kb], acc, 0, 0, 0);
#pragma unroll
            for (int kb = 0; kb < 4; ++kb)  // hilo
                acc = __builtin_amdgcn_mfma_f32_32x32x16_f16(ah[kb].h, bq[kb + 4], acc, 0, 0, 0);
        }
        {
            u4h8 al[4];
#pragma unroll
            for (int kb = 0; kb < 4; ++kb) al[kb].v = buf[bi][4 + kb][lane];
#pragma unroll
            for (int kb = 0; kb < 4; ++kb)  // lohi
                acc = __builtin_amdgcn_mfma_f32_32x32x16_f16(al[kb].h, bq[kb], acc, 0, 0, 0);
            half8 av = {};
            union { unsigned u; _Float16 hh[2]; } cu;
            cu.u = av_u[t];
            av[0] = cu.hh[0]; av[1] = cu.hh[1];
            acc = __builtin_amdgcn_mfma_f32_32x32x16_f16(av, bnc, acc, 0, 0, 0);
        }

        // branchless packed top-3: 16 x (pack ~5 ops + 5-op u64 max/min net)
#pragma unroll
        for (int j = 0; j < 16; ++j) {
            const int li = t * 32 + hi4 + (j & 3) + 8 * (j >> 2);  // local idx
            const u64 u = ((u64)ordf(acc[j]) << 32) | (unsigned)(511 - li);
            const u64 t0 = k0 > u ? k0 : u;
            const u64 b0 = k0 > u ? u : k0;
            const u64 t1 = k1 > b0 ? k1 : b0;
            const u64 b1 = k1 > b0 ? b0 : k1;
            const u64 t2 = k2 > b1 ? k2 : b1;
            k0 = t0; k1 = t1; k2 = t2;
        }
        __syncthreads();  // tile t consumed; buffer safe to overwrite
    }

    // merge lane-halves: capture other half's FULL list first, then insert
    // its 3 values sequentially (disjoint idx bits -> no duplicates).
    const u64 ou0 = __shfl_xor(k0, 32);
    const u64 ou1 = __shfl_xor(k1, 32);
    const u64 ou2 = __shfl_xor(k2, 32);
    const u64 ous[3] = {ou0, ou1, ou2};
#pragma unroll
    for (int r = 0; r < 3; ++r) {
        const u64 u = ous[r];
        const u64 t0 = k0 > u ? k0 : u;
        const u64 b0 = k0 > u ? u : k0;
        const u64 t1 = k1 > b0 ? k1 : b0;
        const u64 b1 = k1 > b0 ? b0 : k1;
        const u64 t2 = k2 > b1 ? k2 : b1;
        k0 = t0; k1 = t1; k2 = t2;
    }
    if (lane < 32) {
        const int q = qg * 32 + lane;
        u64* o = pk + ((size_t)(b * SPL + s) * NN + q) * 3;
        o[0] = k0; o[1] = k1; o[2] = k2;
    }
}

// ---------------------------------------------------------------------------
// K3: merge SPL packed top-3 lists. Decode: key = u >> 32 (exact ordered
// fp32 key), gidx = s*512 + 511 - (u & 511). Select 3 by (key desc,
// gidx asc) lexicographic — exact cross-split semantics.
// ---------------------------------------------------------------------------
__global__ __launch_bounds__(256) void k_merge(const u64* __restrict__ pk,
                                               int* __restrict__ fi) {
    const int t = blockIdx.x * 256 + threadIdx.x;
    if (t >= BB * NN) return;
    const int b = t / NN, n = t % NN;
    unsigned kv[3 * SPL]; int iv[3 * SPL];
#pragma unroll
    for (int s = 0; s < SPL; ++s) {
        const u64* p = pk + ((size_t)(b * SPL + s) * NN + n) * 3;
#pragma unroll
        for (int r = 0; r < 3; ++r) {
            const u64 u = p[r];
            kv[s * 3 + r] = (unsigned)(u >> 32);
            iv[s * 3 + r] = s * 512 + 511 - (int)(u & 511u);
        }
    }
    unsigned bk = 0xFFFFFFFFu; int bi = -1;
#pragma unroll
    for (int r = 0; r < 3; ++r) {
        unsigned ck = 0u; int ci = 0x7fffffff;
#pragma unroll
        for (int j = 0; j < 3 * SPL; ++j) {
            const bool after_prev = (kv[j] < bk) || (kv[j] == bk && iv[j] > bi);
            const bool better = (kv[j] > ck) || (kv[j] == ck && iv[j] < ci);
            if (after_prev && better) { ck = kv[j]; ci = iv[j]; }
        }
        fi[(size_t)t * 3 + r] = ci;
        bk = ck; bi = ci;
    }
}

// ---------------------------------------------------------------------------
// K4: MFMA conv. Block = 64 points x 64 co, 4 waves. A = gathered hi-fp16
// fragments straight from xe (kb 0..3), B = pre-packed Wf.
// Epilogue: bias + relu -> padded LDS transpose -> coalesced stores.
// ---------------------------------------------------------------------------
__global__ __launch_bounds__(256) void k_conv(const uint4* __restrict__ xe,
                                              const uint4* __restrict__ Wf,
                                              const int* __restrict__ fi,
                                              const float* __restrict__ bias,
                                              float* __restrict__ out) {
    __shared__ float ot[64][65];
    const int b = blockIdx.y;
    const int n0 = blockIdx.x * 64;
    const int tid = threadIdx.x;
    const int l = tid & 63;
    const int w = tid >> 6;
    const int mt = w >> 1, ct2 = w & 1;
    const int p31 = l & 31, kh = l >> 5;
    const int npt = n0 + mt * 32 + p31;

    f32x16 acc = {};
    const uint4* xb = xe + (size_t)b * 64 * 8 * 64;
    const int fbase3 = (b * NN + npt) * KNN;
#pragma unroll
    for (int kk = 0; kk < KNN; ++kk) {
        const int src = fi[fbase3 + kk];
        const uint4* ap = xb + (size_t)(src >> 5) * 512 + (src & 31) + 32 * kh;
        uint4 af[4], bw[4];
#pragma unroll
        for (int kb = 0; kb < 4; ++kb) af[kb] = ap[(size_t)kb * 64];
#pragma unroll
        for (int kb = 0; kb < 4; ++kb) bw[kb] = Wf[((kk * 2 + ct2) * 4 + kb) * 64 + l];
#pragma unroll
        for (int kb = 0; kb < 4; ++kb) {
            u4h8 ua, ub;
            ua.v = af[kb]; ub.v = bw[kb];
            acc = __builtin_amdgcn_mfma_f32_32x32x16_f16(ua.h, ub.h, acc, 0, 0, 0);
        }
    }
    const int co = ct2 * 32 + p31;
    const float bv = bias[co];
#pragma unroll
    for (int j = 0; j < 16; ++j) {
        const int pt = mt * 32 + (j & 3) + 8 * (j >> 2) + 4 * kh;
        ot[co][pt] = fmaxf(acc[j] + bv, 0.f);
    }
    __syncthreads();
#pragma unroll
    for (int i = 0; i < 16; ++i) {
        const int v = tid + 256 * i;
        const int co2 = v >> 6, col = v & 63;
        out[((size_t)(b * COUT + co2)) * NN + n0 + col] = ot[co2][col];
    }
}

extern "C" void kernel_launch(void* const* d_in, const int* in_sizes, int n_in,
                              void* d_out, int out_size, void* d_ws, size_t ws_size,
                              hipStream_t stream) {
    const float* x = (const float*)d_in[0];
    const float* W = (const float*)d_in[1];
    const float* bias = (const float*)d_in[2];
    float* out = (float*)d_out;

    char* ws = (char*)d_ws;
    uint4* xe = (uint4*)(ws);                       //  8,388,608 B
    unsigned* anc = (unsigned*)(ws + 8388608);      //    131,072 B
    uint4* Wf = (uint4*)(ws + 8519680);             //     24,576 B
    u64* pk = (u64*)(ws + 8544256);                 //  3,145,728 B
    int* fi = (int*)(ws + 11689984);                //    393,216 B (end ~12.1 MB)

    k_prep<<<dim3(BB, NN / 64), 256, 0, stream>>>(x, xe, anc);
    k_wprep<<<1, 256, 0, stream>>>(W, Wf);
    k_top3<<<dim3(8 * 64), 512, 0, stream>>>(xe, anc, pk);
    k_merge<<<(BB * NN + 255) / 256, 256, 0, stream>>>(pk, fi);
    k_conv<<<dim3(NN / 64, BB), 256, 0, stream>>>(xe, Wf, fi, bias, out);
}

// Round 15
// 72.248 us; speedup vs baseline: 1.1445x; 1.1445x over previous
//
#include <hip/hip_runtime.h>
#include <float.h>

#define BB 16
#define CC 64
#define NN 2048
#define KNN 3
#define COUT 64
#define SPL 4      // candidate splits; 512 cands/split -> 9-bit local idx
#define TILES 16   // 32-cand tiles per split

typedef _Float16 half8 __attribute__((ext_vector_type(8)));
typedef float f32x16 __attribute__((ext_vector_type(16)));

union u4h8 { uint4 v; half8 h; };

// async global->LDS, 16B per lane, wave-uniform LDS base (HW adds lane*16)
__device__ __forceinline__ void gl_lds16(const void* g, void* l) {
    __builtin_amdgcn_global_load_lds(
        (const __attribute__((address_space(1))) unsigned*)g,
        (__attribute__((address_space(3))) unsigned*)l, 16, 0, 0);
}

// ---------------------------------------------------------------------------
// K1: from x[b][c][n] produce:
//   xe[b][ct][kblk][lane] (16B fp16x8 MFMA fragments of ext=[hi|lo], K=128)
//   anc[b][ct][l<32] (packed fp16 pair (-nc/2 hi, -nc/2 lo))
// Fragment convention: row m = lane&31, k = kblk*16 + 8*(lane>>5) + j.
// kblk 0..3 = hi(x[c]) (c = k), kblk 4..7 = lo residual (c = k-64).
// ---------------------------------------------------------------------------
__global__ __launch_bounds__(256) void k_prep(const float* __restrict__ x,
                                              uint4* __restrict__ xe,
                                              unsigned* __restrict__ anc) {
    __shared__ float t[64][65];
    __shared__ float nsh[64];
    const int b = blockIdx.x;
    const int n0 = blockIdx.y * 64;
    const int tid = threadIdx.x;
    const int ln = tid & 63, g = tid >> 6;
#pragma unroll
    for (int i = 0; i < 16; ++i) {
        const int c = g + 4 * i;
        t[c][ln] = x[((size_t)b * CC + c) * NN + n0 + ln];
    }
    __syncthreads();
    if (tid < 64) {
        float s = 0.f;
#pragma unroll
        for (int c = 0; c < 64; ++c) s = fmaf(t[c][tid], t[c][tid], s);
        nsh[tid] = s;
    }
#pragma unroll
    for (int i = 0; i < 4; ++i) {
        const int cid = tid + 256 * i;
        const int lane = cid & 63;
        const int kblk = (cid >> 6) & 7;
        const int ctl = cid >> 9;               // 0..1
        const int m = ctl * 32 + (lane & 31);   // local point
        const int khalf = (lane >> 5) * 8;
        union { uint4 v; _Float16 h[8]; } pk;
#pragma unroll
        for (int j = 0; j < 8; ++j) {
            const int kg = kblk * 16 + khalf + j;
            const int ch = kg & 63;
            const float f = t[ch][m];
            const _Float16 hi = (_Float16)f;
            pk.h[j] = (kg < 64) ? hi : (_Float16)(f - (float)hi);
        }
        const int ct = (n0 >> 5) + ctl;
        xe[((size_t)(b * 64 + ct) * 8 + kblk) * 64 + lane] = pk.v;
    }
    __syncthreads();
    if (tid < 64) {
        const int ctl = tid >> 5, l = tid & 31;
        const int ct = (n0 >> 5) + ctl;
        const float h = -0.5f * nsh[ctl * 32 + l];
        const _Float16 a0 = (_Float16)h;
        const _Float16 a1 = (_Float16)(h - (float)a0);
        union { unsigned u; _Float16 hh[2]; } cu;
        cu.hh[0] = a0; cu.hh[1] = a1;
        anc[(size_t)(b * 64 + ct) * 32 + l] = cu.u;
    }
}

// ---------------------------------------------------------------------------
// K1b: pack W into fp16 B-fragments. Wf[((kk*2+ct2)*4+kb)*64 + lane]:
// co = ct2*32 + (lane&31), c = kb*16 + 8*(lane>>5) + j, value = fp16(W[co][c][kk])
// ---------------------------------------------------------------------------
__global__ __launch_bounds__(256) void k_wprep(const float* __restrict__ W,
                                               uint4* __restrict__ Wf) {
    const int tid = threadIdx.x;
#pragma unroll
    for (int i = 0; i < 6; ++i) {
        const int id = tid + 256 * i;
        const int l = id & 63;
        const int kb = (id >> 6) & 3;
        const int ct2 = (id >> 8) & 1;
        const int kk = id >> 9;
        const int co = ct2 * 32 + (l & 31);
        union { uint4 v; _Float16 h[8]; } pk;
#pragma unroll
        for (int j = 0; j < 8; ++j) {
            const int c = kb * 16 + 8 * (l >> 5) + j;
            pk.h[j] = (_Float16)W[(co * CC + c) * KNN + kk];
        }
        Wf[id] = pk.v;
    }
}

// ---------------------------------------------------------------------------
// K2: MFMA top-3, branchless f32+index bubble network (~14 instr/elem,
// exact fp32 keys — r12/r13 truncation flipped ranks; r14 u64 was 29/elem).
// Scan ascending + strict > == lax.top_k lower-index tie-break (new elem
// always has the highest index seen; on tie it demotes).
// Block = 8 waves, QG=1/wave, depth-1 LDS dbuf of candidate tiles (r11).
// 13 MFMA/tile (hihi/hilo/lohi + norm; lolo < 1e-6, dropped).
// bid = qb*64 + (b*4+s): blocks sharing candidate range (b,s) share XCD.
// ---------------------------------------------------------------------------
__global__ __launch_bounds__(512, 4) void k_top3(const uint4* __restrict__ xe,
                                                 const unsigned* __restrict__ anc,
                                                 uint4* __restrict__ pk) {
    __shared__ uint4 buf[2][8][64];  // 2 x 8KB candidate tiles
    const int bid = blockIdx.x;      // 512 blocks
    const int qb = bid >> 6;         // query block 0..7
    const int rem = bid & 63;
    const int b = rem >> 2;
    const int s = rem & 3;

    const int tid = threadIdx.x;
    const int lane = tid & 63;
    const int w = tid >> 6;          // wave 0..7
    const int qg = qb * 8 + w;       // this wave's query group (32 queries)

    const uint4* xb = xe + (size_t)(b * 64) * 512;  // tile stride 8*64 uint4
    const int ct0 = s * TILES;

    // prologue: stage tile 0 (1 KB chunk per wave)
    gl_lds16(xb + ((size_t)ct0 * 8 + w) * 64 + lane, &buf[0][w][0]);

    half8 bq[8];
#pragma unroll
    for (int kb = 0; kb < 8; ++kb) {
        u4h8 tq;
        tq.v = xe[((size_t)(b * 64 + qg) * 8 + kb) * 64 + lane];
        bq[kb] = tq.h;
    }
    unsigned av_u[TILES];
#pragma unroll
    for (int t = 0; t < TILES; ++t)
        av_u[t] = anc[(size_t)(b * 64 + ct0 + t) * 32 + (lane & 31)];

    half8 bnc = {};
    if (lane < 32) { bnc[0] = (_Float16)1.0f; bnc[1] = (_Float16)1.0f; }

    float k0 = -FLT_MAX, k1 = -FLT_MAX, k2 = -FLT_MAX;
    int i0 = 0, i1 = 0, i2 = 0;
    const int hi4 = (lane >> 5) * 4;

    __syncthreads();

#pragma unroll
    for (int t = 0; t < TILES; ++t) {
        const int bi = t & 1;
        if (t + 1 < TILES)  // stage next tile into the buffer freed at t-1
            gl_lds16(xb + ((size_t)(ct0 + t + 1) * 8 + w) * 64 + lane,
                     &buf[bi ^ 1][w][0]);

        f32x16 acc = {};
        {
            u4h8 ah[4];
#pragma unroll
            for (int kb = 0; kb < 4; ++kb) ah[kb].v = buf[bi][kb][lane];
#pragma unroll
            for (int kb = 0; kb < 4; ++kb)  // hihi
                acc = __builtin_amdgcn_mfma_f32_32x32x16_f16(ah[kb].h, bq[kb], acc, 0, 0, 0);
#pragma unroll
            for (int kb = 0; kb < 4; ++kb)  // hilo
                acc = __builtin_amdgcn_mfma_f32_32x32x16_f16(ah[kb].h, bq[kb + 4], acc, 0, 0, 0);
        }
        {
            u4h8 al[4];
#pragma unroll
            for (int kb = 0; kb < 4; ++kb) al[kb].v = buf[bi][4 + kb][lane];
#pragma unroll
            for (int kb = 0; kb < 4; ++kb)  // lohi
                acc = __builtin_amdgcn_mfma_f32_32x32x16_f16(al[kb].h, bq[kb], acc, 0, 0, 0);
            half8 av = {};
            union { unsigned u; _Float16 hh[2]; } cu;
            cu.u = av_u[t];
            av[0] = cu.hh[0]; av[1] = cu.hh[1];
            acc = __builtin_amdgcn_mfma_f32_32x32x16_f16(av, bnc, acc, 0, 0, 0);
        }

        // branchless 3-level bubble: cmp+max+min+2 cndmask per level (~14/elem)
        const int libase = t * 32 + hi4;
#pragma unroll
        for (int j = 0; j < 16; ++j) {
            const float a = acc[j];
            const int li = libase + (j & 3) + 8 * (j >> 2);  // local idx
            const bool g0 = a > k0;
            const float d0 = g0 ? k0 : a;  const int di0 = g0 ? i0 : li;
            k0 = g0 ? a : k0;              i0 = g0 ? li : i0;
            const bool g1 = d0 > k1;
            const float d1 = g1 ? k1 : d0; const int di1 = g1 ? i1 : di0;
            k1 = g1 ? d0 : k1;             i1 = g1 ? di0 : i1;
            const bool g2 = d1 > k2;
            k2 = g2 ? d1 : k2;             i2 = g2 ? di1 : i2;
        }
        __syncthreads();  // tile t consumed; buffer safe to overwrite
    }

    // merge lane-halves: capture other half's FULL list first, then insert
    // its 3 values with (key desc, idx asc) lexicographic compares.
    const float ok0 = __shfl_xor(k0, 32), ok1 = __shfl_xor(k1, 32), ok2 = __shfl_xor(k2, 32);
    const int oi0 = __shfl_xor(i0, 32), oi1 = __shfl_xor(i1, 32), oi2 = __shfl_xor(i2, 32);
    const float oks[3] = {ok0, ok1, ok2};
    const int ois[3] = {oi0, oi1, oi2};
#pragma unroll
    for (int r = 0; r < 3; ++r) {
        const float c = oks[r]; const int ci = ois[r];
        const bool g0 = (c > k0) || (c == k0 && ci < i0);
        const float d0 = g0 ? k0 : c;  const int di0 = g0 ? i0 : ci;
        k0 = g0 ? c : k0;              i0 = g0 ? ci : i0;
        const bool g1 = (d0 > k1) || (d0 == k1 && di0 < i1);
        const float d1 = g1 ? k1 : d0; const int di1 = g1 ? i1 : di0;
        k1 = g1 ? d0 : k1;             i1 = g1 ? di0 : i1;
        const bool g2 = (d1 > k2) || (d1 == k2 && di1 < i2);
        k2 = g2 ? d1 : k2;             i2 = g2 ? di1 : i2;
    }
    if (lane < 32) {
        const int q = qg * 32 + lane;
        uint4 v;
        v.x = __float_as_uint(k0);
        v.y = __float_as_uint(k1);
        v.z = __float_as_uint(k2);
        v.w = (unsigned)i0 | ((unsigned)i1 << 9) | ((unsigned)i2 << 18);  // 27b
        pk[((size_t)b * SPL + s) * NN + q] = v;
    }
}

// ---------------------------------------------------------------------------
// K3: merge SPL packed top-3 lists, (key desc, global idx asc) lexicographic.
// Global idx = local (9-bit) + s*512. Exact fp32 keys (r8-proven pattern).
// ---------------------------------------------------------------------------
__global__ __launch_bounds__(256) void k_merge(const uint4* __restrict__ pk,
                                               int* __restrict__ fi) {
    const int t = blockIdx.x * 256 + threadIdx.x;
    if (t >= BB * NN) return;
    const int b = t / NN, n = t % NN;
    float dv[3 * SPL]; int iv[3 * SPL];
#pragma unroll
    for (int s = 0; s < SPL; ++s) {
        const uint4 v = pk[((size_t)b * SPL + s) * NN + n];
        dv[s * 3 + 0] = __uint_as_float(v.x);
        dv[s * 3 + 1] = __uint_as_float(v.y);
        dv[s * 3 + 2] = __uint_as_float(v.z);
        iv[s * 3 + 0] = (int)(v.w & 511u) + s * 512;
        iv[s * 3 + 1] = (int)((v.w >> 9) & 511u) + s * 512;
        iv[s * 3 + 2] = (int)((v.w >> 18) & 511u) + s * 512;
    }
    float bd = FLT_MAX; int bi = -1;
#pragma unroll
    for (int r = 0; r < 3; ++r) {
        float ck = -FLT_MAX; int ci = 0x7fffffff;
#pragma unroll
        for (int j = 0; j < 3 * SPL; ++j) {
            const bool after_prev = (dv[j] < bd) || (dv[j] == bd && iv[j] > bi);
            const bool better = (dv[j] > ck) || (dv[j] == ck && iv[j] < ci);
            if (after_prev && better) { ck = dv[j]; ci = iv[j]; }
        }
        fi[(size_t)t * 3 + r] = ci;
        bd = ck; bi = ci;
    }
}

// ---------------------------------------------------------------------------
// K4: MFMA conv. Block = 64 points x 64 co, 4 waves. A = gathered hi-fp16
// fragments straight from xe (kb 0..3), B = pre-packed Wf.
// Epilogue: bias + relu -> padded LDS transpose -> coalesced stores.
// ---------------------------------------------------------------------------
__global__ __launch_bounds__(256) void k_conv(const uint4* __restrict__ xe,
                                              const uint4* __restrict__ Wf,
                                              const int* __restrict__ fi,
                                              const float* __restrict__ bias,
                                              float* __restrict__ out) {
    __shared__ float ot[64][65];
    const int b = blockIdx.y;
    const int n0 = blockIdx.x * 64;
    const int tid = threadIdx.x;
    const int l = tid & 63;
    const int w = tid >> 6;
    const int mt = w >> 1, ct2 = w & 1;
    const int p31 = l & 31, kh = l >> 5;
    const int npt = n0 + mt * 32 + p31;

    f32x16 acc = {};
    const uint4* xb = xe + (size_t)b * 64 * 8 * 64;
    const int fbase3 = (b * NN + npt) * KNN;
#pragma unroll
    for (int kk = 0; kk < KNN; ++kk) {
        const int src = fi[fbase3 + kk];
        const uint4* ap = xb + (size_t)(src >> 5) * 512 + (src & 31) + 32 * kh;
        uint4 af[4], bw[4];
#pragma unroll
        for (int kb = 0; kb < 4; ++kb) af[kb] = ap[(size_t)kb * 64];
#pragma unroll
        for (int kb = 0; kb < 4; ++kb) bw[kb] = Wf[((kk * 2 + ct2) * 4 + kb) * 64 + l];
#pragma unroll
        for (int kb = 0; kb < 4; ++kb) {
            u4h8 ua, ub;
            ua.v = af[kb]; ub.v = bw[kb];
            acc = __builtin_amdgcn_mfma_f32_32x32x16_f16(ua.h, ub.h, acc, 0, 0, 0);
        }
    }
    const int co = ct2 * 32 + p31;
    const float bv = bias[co];
#pragma unroll
    for (int j = 0; j < 16; ++j) {
        const int pt = mt * 32 + (j & 3) + 8 * (j >> 2) + 4 * kh;
        ot[co][pt] = fmaxf(acc[j] + bv, 0.f);
    }
    __syncthreads();
#pragma unroll
    for (int i = 0; i < 16; ++i) {
        const int v = tid + 256 * i;
        const int co2 = v >> 6, col = v & 63;
        out[((size_t)(b * COUT + co2)) * NN + n0 + col] = ot[co2][col];
    }
}

extern "C" void kernel_launch(void* const* d_in, const int* in_sizes, int n_in,
                              void* d_out, int out_size, void* d_ws, size_t ws_size,
                              hipStream_t stream) {
    const float* x = (const float*)d_in[0];
    const float* W = (const float*)d_in[1];
    const float* bias = (const float*)d_in[2];
    float* out = (float*)d_out;

    char* ws = (char*)d_ws;
    uint4* xe = (uint4*)(ws);                       //  8,388,608 B
    unsigned* anc = (unsigned*)(ws + 8388608);      //    131,072 B
    uint4* Wf = (uint4*)(ws + 8519680);             //     24,576 B
    uint4* pk = (uint4*)(ws + 8544256);             //  2,097,152 B
    int* fi = (int*)(ws + 10641408);                //    393,216 B (end ~11.0 MB)

    k_prep<<<dim3(BB, NN / 64), 256, 0, stream>>>(x, xe, anc);
    k_wprep<<<1, 256, 0, stream>>>(W, Wf);
    k_top3<<<dim3(8 * 64), 512, 0, stream>>>(xe, anc, pk);
    k_merge<<<(BB * NN + 255) / 256, 256, 0, stream>>>(pk, fi);
    k_conv<<<dim3(NN / 64, BB), 256, 0, stream>>>(xe, Wf, fi, bias, out);
}